// Round 1
// baseline (476.076 us; speedup 1.0000x reference)
//
#include <hip/hip_runtime.h>
#include <hip/hip_bf16.h>
#include <cstdint>

#define T_LEN 512
#define B_SZ  256
#define HID   256
#define OUT   128
#define FUSE  384
#define MROWS (T_LEN * B_SZ)   // 131072

// ---------------- K1: x_proj = [vis|imu|traj] @ W_in + b_in ----------------
// C[M=131072, N=256] = A[M,384] (gathered from 3 tensors) @ B[384,256]
#define K1_BM 128
#define K1_BN 128
#define K1_BK 16

__global__ __launch_bounds__(256) void k1_xproj(
    const float* __restrict__ vis, const float* __restrict__ imu,
    const float* __restrict__ traj, const float* __restrict__ Win,
    const float* __restrict__ bin, float* __restrict__ xproj)
{
  __shared__ float As[K1_BK][K1_BM + 4];
  __shared__ float Bs[K1_BK][K1_BN + 4];
  const int tid  = threadIdx.x;
  const int brow = blockIdx.y * K1_BM;
  const int bcol = blockIdx.x * K1_BN;
  const int tx = tid & 15, ty = tid >> 4;

  float acc[8][8];
#pragma unroll
  for (int i = 0; i < 8; ++i)
#pragma unroll
    for (int j = 0; j < 8; ++j) acc[i][j] = 0.f;

  for (int k0 = 0; k0 < FUSE; k0 += K1_BK) {
    // A tile: 128 rows x 16 k, gathered. float4 per slot; 2 slots/thread.
#pragma unroll
    for (int s = 0; s < 2; ++s) {
      int slot = tid + s * 256;          // 0..511
      int row  = slot >> 2;              // 0..127
      int kq   = (slot & 3) << 2;        // 0,4,8,12
      int m = brow + row;
      int k = k0 + kq;
      const float* src; int off;
      if (k < 256)      { src = vis;  off = m * 256 + k; }
      else if (k < 320) { src = imu;  off = m * 64 + (k - 256); }
      else              { src = traj; off = m * 64 + (k - 320); }
      float4 v = *reinterpret_cast<const float4*>(src + off);
      As[kq + 0][row] = v.x; As[kq + 1][row] = v.y;
      As[kq + 2][row] = v.z; As[kq + 3][row] = v.w;
    }
    // B tile: 16 k x 128 cols from W_in [384,256]
#pragma unroll
    for (int s = 0; s < 2; ++s) {
      int slot = tid + s * 256;
      int kr = slot >> 5;                // 0..15
      int cq = (slot & 31) << 2;         // 0..124
      float4 v = *reinterpret_cast<const float4*>(Win + (k0 + kr) * HID + bcol + cq);
      *reinterpret_cast<float4*>(&Bs[kr][cq]) = v;
    }
    __syncthreads();
#pragma unroll
    for (int kk = 0; kk < K1_BK; ++kk) {
      float4 a0 = *reinterpret_cast<const float4*>(&As[kk][ty * 8]);
      float4 a1 = *reinterpret_cast<const float4*>(&As[kk][ty * 8 + 4]);
      float4 b0 = *reinterpret_cast<const float4*>(&Bs[kk][tx * 8]);
      float4 b1 = *reinterpret_cast<const float4*>(&Bs[kk][tx * 8 + 4]);
      float a[8] = {a0.x, a0.y, a0.z, a0.w, a1.x, a1.y, a1.z, a1.w};
      float b[8] = {b0.x, b0.y, b0.z, b0.w, b1.x, b1.y, b1.z, b1.w};
#pragma unroll
      for (int i = 0; i < 8; ++i)
#pragma unroll
        for (int j = 0; j < 8; ++j) acc[i][j] += a[i] * b[j];
    }
    __syncthreads();
  }
#pragma unroll
  for (int i = 0; i < 8; ++i) {
    int m = brow + ty * 8 + i;
#pragma unroll
    for (int jq = 0; jq < 2; ++jq) {
      int n = bcol + tx * 8 + jq * 4;
      float4 v;
      v.x = acc[i][jq * 4 + 0] + bin[n + 0];
      v.y = acc[i][jq * 4 + 1] + bin[n + 1];
      v.z = acc[i][jq * 4 + 2] + bin[n + 2];
      v.w = acc[i][jq * 4 + 3] + bin[n + 3];
      *reinterpret_cast<float4*>(xproj + (size_t)m * HID + n) = v;
    }
  }
}

// ---------------- K2: RLIF scan over t; spikes -> bitmasks + counts --------
__global__ __launch_bounds__(256) void k2_scan(
    const float* __restrict__ xproj, const float* __restrict__ wrec,
    uint32_t* __restrict__ sbits, float* __restrict__ scnt)
{
  const int b = blockIdx.x;        // 256 blocks, one per batch element
  const int h = threadIdx.x;       // 256 threads, one per hidden unit
  const int bh = b * HID + h;
  const int lane = h & 63;
  const int wv = h >> 6;           // wave id 0..3 (h-chunk of 64)
  const float wr = wrec[h];
  float V = 0.f, S = 0.f, cnt = 0.f;

  for (int t0 = 0; t0 < T_LEN; t0 += 8) {
    float xv[8];
#pragma unroll
    for (int u = 0; u < 8; ++u)
      xv[u] = xproj[(size_t)(t0 + u) * (B_SZ * HID) + bh];
#pragma unroll
    for (int u = 0; u < 8; ++u) {
      V = 0.9f * V + xv[u] + wr * S;                 // leak + input + recurrent
      float sn = (V - 1.0f > 0.0f) ? 1.0f : 0.0f;    // Heaviside(V - THRESHOLD)
      V -= sn;                                       // soft reset
      cnt += sn;
      S = sn;
      unsigned long long mk = __ballot(sn > 0.5f);   // 64 h-lanes -> bitmask
      if (lane == 0) {
        int m = (t0 + u) * B_SZ + b;
        sbits[(size_t)m * 8 + wv * 2 + 0] = (uint32_t)(mk & 0xffffffffull);
        sbits[(size_t)m * 8 + wv * 2 + 1] = (uint32_t)(mk >> 32);
      }
    }
  }
  scnt[bh] = cnt;
}

// ---------------- K3: logits = spikes @ W_head + b_head --------------------
// C[M=131072, N=128] = bits[M,256] @ W_head[256,128]
#define K3_BM 128
#define K3_BK 32

__global__ __launch_bounds__(256) void k3_logits(
    const uint32_t* __restrict__ sbits, const float* __restrict__ Whead,
    const float* __restrict__ bhead, float* __restrict__ logits)
{
  __shared__ float As[K3_BK][K3_BM + 4];
  __shared__ float Bs[K3_BK][OUT + 4];
  const int tid  = threadIdx.x;
  const int brow = blockIdx.x * K3_BM;
  const int tx = tid & 15, ty = tid >> 4;

  float acc[8][8];
#pragma unroll
  for (int i = 0; i < 8; ++i)
#pragma unroll
    for (int j = 0; j < 8; ++j) acc[i][j] = 0.f;

  for (int k0 = 0; k0 < HID; k0 += K3_BK) {
    // expand 32 spike bits per row into As
    {
      int row  = tid >> 1;
      int half = tid & 1;
      int m = brow + row;
      uint32_t w = sbits[(size_t)m * 8 + (k0 >> 5)];
#pragma unroll
      for (int j = 0; j < 16; ++j) {
        int k = half * 16 + j;
        As[k][row] = (float)((w >> k) & 1u);
      }
    }
    // B tile: 32 k x 128 cols
#pragma unroll
    for (int s = 0; s < 4; ++s) {
      int slot = tid + s * 256;          // 0..1023
      int kr = slot >> 5;                // 0..31
      int cq = (slot & 31) << 2;         // 0..124
      float4 v = *reinterpret_cast<const float4*>(Whead + (k0 + kr) * OUT + cq);
      *reinterpret_cast<float4*>(&Bs[kr][cq]) = v;
    }
    __syncthreads();
#pragma unroll
    for (int kk = 0; kk < K3_BK; ++kk) {
      float4 a0 = *reinterpret_cast<const float4*>(&As[kk][ty * 8]);
      float4 a1 = *reinterpret_cast<const float4*>(&As[kk][ty * 8 + 4]);
      float4 b0 = *reinterpret_cast<const float4*>(&Bs[kk][tx * 8]);
      float4 b1 = *reinterpret_cast<const float4*>(&Bs[kk][tx * 8 + 4]);
      float a[8] = {a0.x, a0.y, a0.z, a0.w, a1.x, a1.y, a1.z, a1.w};
      float b[8] = {b0.x, b0.y, b0.z, b0.w, b1.x, b1.y, b1.z, b1.w};
#pragma unroll
      for (int i = 0; i < 8; ++i)
#pragma unroll
        for (int j = 0; j < 8; ++j) acc[i][j] += a[i] * b[j];
    }
    __syncthreads();
  }
#pragma unroll
  for (int i = 0; i < 8; ++i) {
    int m = brow + ty * 8 + i;
#pragma unroll
    for (int jq = 0; jq < 2; ++jq) {
      int n = tx * 8 + jq * 4;
      float4 v;
      v.x = acc[i][jq * 4 + 0] + bhead[n + 0];
      v.y = acc[i][jq * 4 + 1] + bhead[n + 1];
      v.z = acc[i][jq * 4 + 2] + bhead[n + 2];
      v.w = acc[i][jq * 4 + 3] + bhead[n + 3];
      *reinterpret_cast<float4*>(logits + (size_t)m * OUT + n) = v;
    }
  }
}

// ---------------- K4: out = (spike_counts / T) @ W_head + b_head ----------
__global__ __launch_bounds__(128) void k4_out(
    const float* __restrict__ scnt, const float* __restrict__ Whead,
    const float* __restrict__ bhead, float* __restrict__ outp)
{
  __shared__ float s[HID];
  const int b = blockIdx.x;
  const int o = threadIdx.x;     // 128 threads
  s[o] = scnt[b * HID + o];
  s[o + 128] = scnt[b * HID + o + 128];
  __syncthreads();
  float acc = 0.f;
#pragma unroll 8
  for (int h = 0; h < HID; ++h) acc += s[h] * Whead[h * OUT + o];
  outp[b * OUT + o] = acc * (1.0f / (float)T_LEN) + bhead[o];
}

extern "C" void kernel_launch(void* const* d_in, const int* in_sizes, int n_in,
                              void* d_out, int out_size, void* d_ws, size_t ws_size,
                              hipStream_t stream)
{
  const float* vis   = (const float*)d_in[0];
  const float* imu   = (const float*)d_in[1];
  const float* traj  = (const float*)d_in[2];
  const float* Win   = (const float*)d_in[3];
  const float* bin   = (const float*)d_in[4];
  const float* wrec  = (const float*)d_in[5];
  const float* Whead = (const float*)d_in[6];
  const float* bhead = (const float*)d_in[7];

  float* outp   = (float*)d_out;            // [B, OUT] first (return order)
  float* logits = outp + B_SZ * OUT;        // [T, B, OUT]

  char* ws = (char*)d_ws;
  float*    xproj = (float*)ws;                                     // 134.2 MB
  uint32_t* sbits = (uint32_t*)(ws + (size_t)MROWS * HID * 4);      // 4.2 MB
  float*    scnt  = (float*)(ws + (size_t)MROWS * HID * 4
                                + (size_t)MROWS * 8 * 4);           // 0.26 MB

  k1_xproj<<<dim3(HID / K1_BN, MROWS / K1_BM), 256, 0, stream>>>(
      vis, imu, traj, Win, bin, xproj);
  k2_scan<<<dim3(B_SZ), 256, 0, stream>>>(xproj, wrec, sbits, scnt);
  k3_logits<<<dim3(MROWS / K3_BM), 256, 0, stream>>>(sbits, Whead, bhead, logits);
  k4_out<<<dim3(B_SZ), 128, 0, stream>>>(scnt, Whead, bhead, outp);
}

// Round 5
// 432.839 us; speedup vs baseline: 1.0999x; 1.0999x over previous
//
#include <hip/hip_runtime.h>
#include <hip/hip_bf16.h>
#include <cstdint>

#define T_LEN 512
#define B_SZ  256
#define HID   256
#define OUT   128
#define FUSE  384
#define MROWS (T_LEN * B_SZ)   // 131072

typedef _Float16 f16x8 __attribute__((ext_vector_type(8)));
typedef float f32x4 __attribute__((ext_vector_type(4)));

// ---------------- K1: x_proj = [vis|imu|traj] @ W_in + b_in ----------------
// fp32 vector-FMA, per-element arithmetic IDENTICAL to round-1's passing
// kernel (ascending-k fused FMA chain, bias added at store). 256x128 tile,
// 512 threads, 8x8 per-thread tile, BK=32, register prefetch of next chunk.
#define K1_BM 256
#define K1_BN 128
#define K1_BK 32

__global__ __launch_bounds__(512) void k1_xproj(
    const float* __restrict__ vis, const float* __restrict__ imu,
    const float* __restrict__ traj, const float* __restrict__ Win,
    const float* __restrict__ bin, float* __restrict__ xproj)
{
  __shared__ float As[K1_BK][K1_BM + 4];
  __shared__ float Bs[K1_BK][K1_BN + 4];
  const int tid  = threadIdx.x;
  const int brow = blockIdx.y * K1_BM;
  const int bcol = blockIdx.x * K1_BN;
  const int tx = tid & 15, ty = tid >> 4;   // tx: 16 x 8 cols, ty: 32 x 8 rows

  float acc[8][8];
#pragma unroll
  for (int i = 0; i < 8; ++i)
#pragma unroll
    for (int j = 0; j < 8; ++j) acc[i][j] = 0.f;

  float4 pa[4];   // A prefetch: 4 slots x float4
  float4 pb[2];   // B prefetch: 2 slots x float4

  auto loadT = [&](int c) {
    // A: 256 rows x 32 k = 2048 float4 slots / 512 threads = 4 each
#pragma unroll
    for (int s = 0; s < 4; ++s) {
      int slot = tid + s * 512;          // 0..2047
      int row  = slot >> 3;              // 0..255
      int kq   = (slot & 7) << 2;        // 0..28
      size_t m = brow + row;
      int k = c * 32 + kq;
      const float* src; size_t off;
      if (k < 256)      { src = vis;  off = m * 256 + k; }
      else if (k < 320) { src = imu;  off = m * 64 + (k - 256); }
      else              { src = traj; off = m * 64 + (k - 320); }
      pa[s] = *reinterpret_cast<const float4*>(src + off);
    }
    // B: 32 k x 128 cols = 1024 float4 slots / 512 = 2 each
#pragma unroll
    for (int s = 0; s < 2; ++s) {
      int slot = tid + s * 512;          // 0..1023
      int kr = slot >> 5;                // 0..31
      int cq = (slot & 31) << 2;         // 0..124
      pb[s] = *reinterpret_cast<const float4*>(Win + (size_t)(c * 32 + kr) * HID + bcol + cq);
    }
  };

  loadT(0);

#pragma unroll 1
  for (int c = 0; c < 12; ++c) {
    __syncthreads();                     // previous compute done; LDS free
#pragma unroll
    for (int s = 0; s < 4; ++s) {
      int slot = tid + s * 512;
      int row  = slot >> 3;
      int kq   = (slot & 7) << 2;
      As[kq + 0][row] = pa[s].x; As[kq + 1][row] = pa[s].y;
      As[kq + 2][row] = pa[s].z; As[kq + 3][row] = pa[s].w;
    }
#pragma unroll
    for (int s = 0; s < 2; ++s) {
      int slot = tid + s * 512;
      int kr = slot >> 5;
      int cq = (slot & 31) << 2;
      *reinterpret_cast<float4*>(&Bs[kr][cq]) = pb[s];
    }
    __syncthreads();                     // tile ready
    if (c + 1 < 12) loadT(c + 1);        // prefetch flies under the FMAs

#pragma unroll
    for (int kk = 0; kk < K1_BK; ++kk) {
      float4 a0 = *reinterpret_cast<const float4*>(&As[kk][ty * 8]);
      float4 a1 = *reinterpret_cast<const float4*>(&As[kk][ty * 8 + 4]);
      float4 b0 = *reinterpret_cast<const float4*>(&Bs[kk][tx * 8]);
      float4 b1 = *reinterpret_cast<const float4*>(&Bs[kk][tx * 8 + 4]);
      float a[8] = {a0.x, a0.y, a0.z, a0.w, a1.x, a1.y, a1.z, a1.w};
      float b[8] = {b0.x, b0.y, b0.z, b0.w, b1.x, b1.y, b1.z, b1.w};
#pragma unroll
      for (int i = 0; i < 8; ++i)
#pragma unroll
        for (int j = 0; j < 8; ++j) acc[i][j] += a[i] * b[j];
    }
  }

#pragma unroll
  for (int i = 0; i < 8; ++i) {
    int m = brow + ty * 8 + i;
#pragma unroll
    for (int jq = 0; jq < 2; ++jq) {
      int n = bcol + tx * 8 + jq * 4;
      float4 v;
      v.x = acc[i][jq * 4 + 0] + bin[n + 0];
      v.y = acc[i][jq * 4 + 1] + bin[n + 1];
      v.z = acc[i][jq * 4 + 2] + bin[n + 2];
      v.w = acc[i][jq * 4 + 3] + bin[n + 3];
      *reinterpret_cast<float4*>(xproj + (size_t)m * HID + n) = v;
    }
  }
}

// ---------------- K2: RLIF scan (round-1 verbatim — proven bit-exact) ------
__global__ __launch_bounds__(256) void k2_scan(
    const float* __restrict__ xproj, const float* __restrict__ wrec,
    uint32_t* __restrict__ sbits, float* __restrict__ scnt)
{
  const int b = blockIdx.x;
  const int h = threadIdx.x;
  const int bh = b * HID + h;
  const int lane = h & 63;
  const int wv = h >> 6;
  const float wr = wrec[h];
  float V = 0.f, S = 0.f, cnt = 0.f;

  for (int t0 = 0; t0 < T_LEN; t0 += 8) {
    float xv[8];
#pragma unroll
    for (int u = 0; u < 8; ++u)
      xv[u] = xproj[(size_t)(t0 + u) * (B_SZ * HID) + bh];
#pragma unroll
    for (int u = 0; u < 8; ++u) {
      V = 0.9f * V + xv[u] + wr * S;
      float sn = (V - 1.0f > 0.0f) ? 1.0f : 0.0f;
      V -= sn;
      cnt += sn;
      S = sn;
      unsigned long long mk = __ballot(sn > 0.5f);
      if (lane == 0) {
        int m = (t0 + u) * B_SZ + b;
        sbits[(size_t)m * 8 + wv * 2 + 0] = (uint32_t)(mk & 0xffffffffull);
        sbits[(size_t)m * 8 + wv * 2 + 1] = (uint32_t)(mk >> 32);
      }
    }
  }
  scnt[bh] = cnt;
}

// ---------------- prep2: W_head fp16 n-major chunked [c=8][n=128][k=32]
__global__ __launch_bounds__(256) void prep_whead(const float* __restrict__ Wh,
                                                  _Float16* __restrict__ Wh3)
{
  int id = blockIdx.x * 256 + threadIdx.x;   // 32768
  int n = id & 127, kk = (id >> 7) & 31, c = id >> 12;
  Wh3[((size_t)c * 128 + n) * 32 + kk] = (_Float16)Wh[(c * 32 + kk) * OUT + n];
}

// ---------------- K3: logits = spikes @ W_head + b_head  (fp16 MFMA) -------
#define LDA 40
__global__ __launch_bounds__(256) void k3_logits(
    const uint32_t* __restrict__ sbits, const _Float16* __restrict__ Wh3,
    const float* __restrict__ bhead, float* __restrict__ logits)
{
  __shared__ __align__(16) _Float16 Sa[128][LDA];
  __shared__ __align__(16) _Float16 Wt[128][LDA];

  const int tid  = threadIdx.x;
  const int brow = blockIdx.x * 128;
  const int srow = tid >> 1, sks = (tid & 1) << 4;
  const int wid = tid >> 6, lane = tid & 63;
  const int wr = wid >> 1, wc = wid & 1;
  const int fr = lane & 15, fq = lane >> 4;

  f32x4 acc[4][4] = {};
  uint32_t wbits;
  uint4 wb0, wb1;

  auto loadS = [&](int c) { wbits = sbits[(size_t)(brow + srow) * 8 + c]; };
  auto loadW = [&](int c) {
    const _Float16* p = Wh3 + ((size_t)c * 128 + srow) * 32 + sks;
    wb0 = *reinterpret_cast<const uint4*>(p);
    wb1 = *reinterpret_cast<const uint4*>(p + 8);
  };

  loadS(0); loadW(0);

  for (int c = 0; c < 8; ++c) {
    __syncthreads();
    {
      f16x8 e0, e1;
#pragma unroll
      for (int j = 0; j < 8; ++j) {
        e0[j] = (_Float16)(float)((wbits >> (sks + j)) & 1u);
        e1[j] = (_Float16)(float)((wbits >> (sks + 8 + j)) & 1u);
      }
      *reinterpret_cast<f16x8*>(&Sa[srow][sks])     = e0;
      *reinterpret_cast<f16x8*>(&Sa[srow][sks + 8]) = e1;
    }
    *reinterpret_cast<uint4*>(&Wt[srow][sks])     = wb0;
    *reinterpret_cast<uint4*>(&Wt[srow][sks + 8]) = wb1;
    __syncthreads();
    if (c + 1 < 8) { loadS(c + 1); loadW(c + 1); }

    f16x8 wf[4];
#pragma unroll
    for (int nf = 0; nf < 4; ++nf)
      wf[nf] = *reinterpret_cast<const f16x8*>(&Wt[wc * 64 + nf * 16 + fr][fq * 8]);
#pragma unroll
    for (int mf = 0; mf < 4; ++mf) {
      f16x8 sf = *reinterpret_cast<const f16x8*>(&Sa[wr * 64 + mf * 16 + fr][fq * 8]);
#pragma unroll
      for (int nf = 0; nf < 4; ++nf)
        acc[mf][nf] = __builtin_amdgcn_mfma_f32_16x16x32_f16(sf, wf[nf], acc[mf][nf], 0, 0, 0);
    }
  }

#pragma unroll
  for (int mf = 0; mf < 4; ++mf)
#pragma unroll
    for (int nf = 0; nf < 4; ++nf) {
      int n = wc * 64 + nf * 16 + fr;
      float bv = bhead[n];
#pragma unroll
      for (int r = 0; r < 4; ++r) {
        int m = brow + wr * 64 + mf * 16 + fq * 4 + r;
        logits[(size_t)m * OUT + n] = acc[mf][nf][r] + bv;
      }
    }
}

// ---------------- K4: out = (spike_counts / T) @ W_head + b_head (fp32) ----
__global__ __launch_bounds__(128) void k4_out(
    const float* __restrict__ scnt, const float* __restrict__ Whead,
    const float* __restrict__ bhead, float* __restrict__ outp)
{
  __shared__ float s[HID];
  const int b = blockIdx.x;
  const int o = threadIdx.x;
  s[o] = scnt[b * HID + o];
  s[o + 128] = scnt[b * HID + o + 128];
  __syncthreads();
  float acc = 0.f;
#pragma unroll 8
  for (int h = 0; h < HID; ++h) acc += s[h] * Whead[h * OUT + o];
  outp[b * OUT + o] = acc * (1.0f / (float)T_LEN) + bhead[o];
}

extern "C" void kernel_launch(void* const* d_in, const int* in_sizes, int n_in,
                              void* d_out, int out_size, void* d_ws, size_t ws_size,
                              hipStream_t stream)
{
  const float* vis   = (const float*)d_in[0];
  const float* imu   = (const float*)d_in[1];
  const float* traj  = (const float*)d_in[2];
  const float* Win   = (const float*)d_in[3];
  const float* bin   = (const float*)d_in[4];
  const float* wrec  = (const float*)d_in[5];
  const float* Whead = (const float*)d_in[6];
  const float* bhead = (const float*)d_in[7];

  float* outp   = (float*)d_out;           // [B, OUT] (return order: out, logits)
  float* logits = outp + B_SZ * OUT;       // [T, B, OUT]

  char* ws = (char*)d_ws;
  const size_t XPROJ_B = (size_t)MROWS * HID * 4;   // 134.2 MB
  const size_t SBITS_B = (size_t)MROWS * 8 * 4;     // 4.2 MB
  float*    xproj = (float*)ws;
  uint32_t* sbits = (uint32_t*)(ws + XPROJ_B);
  float*    scnt  = (float*)(ws + XPROJ_B + SBITS_B);
  // overlay: Wh3 (W_head fp16, 64 KB) at xproj base — written after K2,
  // when xproj is dead, read by K3. No new ws footprint.
  _Float16* Wh3 = (_Float16*)xproj;

  k1_xproj  <<<dim3(HID / K1_BN, MROWS / K1_BM), 512, 0, stream>>>(
      vis, imu, traj, Win, bin, xproj);
  k2_scan   <<<dim3(B_SZ),        256, 0, stream>>>(xproj, wrec, sbits, scnt);
  prep_whead<<<dim3(32768 / 256), 256, 0, stream>>>(Whead, Wh3);
  k3_logits <<<dim3(MROWS / 128), 256, 0, stream>>>(sbits, Wh3, bhead, logits);
  k4_out    <<<dim3(B_SZ),        128, 0, stream>>>(scnt, Whead, bhead, outp);
}